// Round 20
// baseline (111.401 us; speedup 1.0000x reference)
//
#include <hip/hip_runtime.h>
#include <math.h>

#define NV 4
#define NB 2
#define NC 32
#define ND 32
#define NH 128
#define NW 160
#define NG 8
#define HW (NH*NW)
#define NPIX (NB*NH*NW)
#define FEATSZ (NV*NB*HW*NC)
#define QMAX 60
#define TBLK (HW/64)
#define TGRID (TBLK*NV*NB)
#define GUARD 0.01f

#define RCPF(x) __builtin_amdgcn_rcpf(x)

// ---------------------------------------------------------------------------
// Fused prep: blocks [0,2*TGRID) transpose src/ref (vectorized float4 both
// sides); block 2*TGRID computes P = K3@E_src @ inv(K3@E_ref) (f64 inverse).
// ---------------------------------------------------------------------------
__global__ __launch_bounds__(256) void prep_kernel(
    const float* __restrict__ src_feats,
    const float* __restrict__ ref_feats,
    const float* __restrict__ proj,
    float* __restrict__ srcT,
    float* __restrict__ refT,
    float* __restrict__ pw)
{
    __shared__ float lds[NC][65];
    int bid = blockIdx.x;
    if (bid < 2*TGRID) {
        int which = bid >= TGRID;
        int tb = which ? bid - TGRID : bid;
        const float* in = which ? ref_feats : src_feats;
        float* outp     = which ? refT : srcT;
        int vb = tb / TBLK;
        int hwbase = (tb % TBLK) * 64;
        int t = threadIdx.x;
        #pragma unroll
        for (int r = 0; r < 2; ++r) {
            int c   = (t >> 4) + r*16;
            int hw4 = (t & 15) * 4;
            float4 f = *(const float4*)&in[(vb*NC + c)*HW + hwbase + hw4];
            lds[c][hw4+0] = f.x;
            lds[c][hw4+1] = f.y;
            lds[c][hw4+2] = f.z;
            lds[c][hw4+3] = f.w;
        }
        __syncthreads();
        {
            int hw = t >> 2;
            int c0 = (t & 3) * 8;
            float o[8];
            #pragma unroll
            for (int k = 0; k < 8; ++k) o[k] = lds[c0+k][hw];
            float* dst = &outp[((size_t)vb*HW + hwbase + hw)*NC + c0];
            *(float4*)(dst)     = make_float4(o[0],o[1],o[2],o[3]);
            *(float4*)(dst + 4) = make_float4(o[4],o[5],o[6],o[7]);
        }
        return;
    }
    // ---- proj block ----
    int t = threadIdx.x;
    if (t >= NB * NV) return;
    int b = t / NV, v = t % NV;
    const float* Eref = proj + ((b*(NV+1) + 0)*2 + 0)*16;
    const float* Kref = proj + ((b*(NV+1) + 0)*2 + 1)*16;
    const float* Esrc = proj + ((b*(NV+1) + (v+1))*2 + 0)*16;
    const float* Ksrc = proj + ((b*(NV+1) + (v+1))*2 + 1)*16;
    float Mr[12], Ms[12];
    for (int i = 0; i < 3; ++i)
        for (int j = 0; j < 4; ++j) {
            float sr = 0.f, ss = 0.f;
            for (int k = 0; k < 3; ++k) {
                sr += Kref[i*4+k] * Eref[k*4+j];
                ss += Ksrc[i*4+k] * Esrc[k*4+j];
            }
            Mr[i*4+j] = sr; Ms[i*4+j] = ss;
        }
    double A[9], a[3];
    for (int i = 0; i < 3; ++i) {
        for (int j = 0; j < 3; ++j) A[i*3+j] = (double)Mr[i*4+j];
        a[i] = (double)Mr[i*4+3];
    }
    double c00 = A[4]*A[8]-A[5]*A[7];
    double c01 = A[5]*A[6]-A[3]*A[8];
    double c02 = A[3]*A[7]-A[4]*A[6];
    double det = A[0]*c00 + A[1]*c01 + A[2]*c02;
    double id  = 1.0/det;
    double Ai[9];
    Ai[0]=c00*id;                 Ai[1]=(A[2]*A[7]-A[1]*A[8])*id; Ai[2]=(A[1]*A[5]-A[2]*A[4])*id;
    Ai[3]=c01*id;                 Ai[4]=(A[0]*A[8]-A[2]*A[6])*id; Ai[5]=(A[2]*A[3]-A[0]*A[5])*id;
    Ai[6]=c02*id;                 Ai[7]=(A[1]*A[6]-A[0]*A[7])*id; Ai[8]=(A[0]*A[4]-A[1]*A[3])*id;
    double R[9], T[3];
    for (int i = 0; i < 3; ++i)
        for (int j = 0; j < 3; ++j) {
            double s = 0.0;
            for (int k = 0; k < 3; ++k) s += (double)Ms[i*4+k] * Ai[k*3+j];
            R[i*3+j] = s;
        }
    for (int i = 0; i < 3; ++i) {
        double s = (double)Ms[i*4+3];
        for (int k = 0; k < 3; ++k) s -= R[i*3+k]*a[k];
        T[i] = s;
    }
    float* o = pw + (b*NV + v)*12;
    for (int i = 0; i < 9; ++i) o[i]   = (float)R[i];
    for (int i = 0; i < 3; ++i) o[9+i] = (float)T[i];
}

// ---------------------------------------------------------------------------
// Main: wave = pixel; half hi owns views {hi, hi+2}. BOTH views' geometry +
// endpoint bbox hoisted above the view loop (vv=1 latency hides under vv=0
// staging). Paired flattened staging, S/T compaction, __expf softmax.
// All FP values/orders identical to R18 (pure reordering).
// ---------------------------------------------------------------------------
__global__ __launch_bounds__(256) void mvs_kernel_g(
    const float* __restrict__ refT,
    const float* __restrict__ srcT,
    const float* __restrict__ depth_hypo,
    const float* __restrict__ w_reg,
    const float* __restrict__ pw,
    float* __restrict__ out)
{
    __shared__ float  Dsc[8][QMAX*8];   // 15360 B
    __shared__ float2 STl[8][QMAX];     // 3840 B

    int tid = blockIdx.x * 256 + threadIdx.x;
    int lane = threadIdx.x & 63;
    int d  = lane & 31;
    int hi = lane >> 5;
    int p  = tid >> 6;
    if (p >= NPIX) return;
    int hslot = threadIdx.x >> 5;
    float*  Dh = &Dsc[hslot][0];
    float2* Sh = &STl[hslot][0];
    int sub = lane & 31;
    int j0  = (2*sub) & 7;

    int w = p % NW;
    int h = (p / NW) % NH;
    int b = p / (NW*NH);
    float xf = (float)w, yf = (float)h;
    float depth = depth_hypo[((b*ND + d)*NH + h)*NW + w];

    float dep0  = __shfl(depth, 0, 32);
    float dep31 = __shfl(depth, 31, 32);

    float wr[NG];
    #pragma unroll
    for (int g = 0; g < NG; ++g) wr[g] = w_reg[g];

    // ================= hoisted geometry for BOTH views =================
    float w00a[2], w01a[2], w10a[2], w11a[2];
    int   xc0a[2], xc1a[2], yc0a[2], yc1a[2];
    int   mnxa[2], mnya[2], bwa[2], Ua[2];

    #pragma unroll
    for (int vv = 0; vv < 2; ++vv) {
        int v = hi + 2*vv;
        const float* RT = pw + (b*NV + v)*12;

        float rx = RT[0]*xf + RT[1]*yf + RT[2];
        float ry = RT[3]*xf + RT[4]*yf + RT[5];
        float rz = RT[6]*xf + RT[7]*yf + RT[8];
        float px_ = rx*depth + RT[9];
        float py_ = ry*depth + RT[10];
        float pz_ = rz*depth + RT[11];
        if (pz_ == 0.f) pz_ = 1e-9f;
        float iz = RCPF(pz_);
        float px = px_*iz, py = py_*iz;
        float fx0 = floorf(px), fy0 = floorf(py);
        int x0i = (int)fx0, y0i = (int)fy0;
        int x1i = x0i + 1, y1i = y0i + 1;
        float wx = px - fx0, wy = py - fy0;

        float vx0 = (x0i >= 0 && x0i < NW) ? 1.f : 0.f;
        float vx1 = (x1i >= 0 && x1i < NW) ? 1.f : 0.f;
        float vy0 = (y0i >= 0 && y0i < NH) ? 1.f : 0.f;
        float vy1 = (y1i >= 0 && y1i < NH) ? 1.f : 0.f;
        w00a[vv] = (1.f-wx)*(1.f-wy) * vx0*vy0;
        w01a[vv] = wx*(1.f-wy)       * vx1*vy0;
        w10a[vv] = (1.f-wx)*wy       * vx0*vy1;
        w11a[vv] = wx*wy             * vx1*vy1;
        xc0a[vv] = min(max(x0i,0),NW-1); xc1a[vv] = min(max(x1i,0),NW-1);
        yc0a[vv] = min(max(y0i,0),NH-1); yc1a[vv] = min(max(y1i,0),NH-1);

        // endpoint-projection bbox
        float pzA = rz*dep0  + RT[11];
        float pzB = rz*dep31 + RT[11];
        if (pzA == 0.f) pzA = 1e-9f;
        if (pzB == 0.f) pzB = 1e-9f;
        bool ok = (pzA > 0.f) == (pzB > 0.f);
        float izA = RCPF(pzA), izB = RCPF(pzB);
        float pxA = (rx*dep0  + RT[9])*izA,  pyA = (ry*dep0  + RT[10])*izA;
        float pxB = (rx*dep31 + RT[9])*izB,  pyB = (ry*dep31 + RT[10])*izB;
        float pxmin = fminf(pxA,pxB) - GUARD, pxmax = fmaxf(pxA,pxB) + GUARD;
        float pymin = fminf(pyA,pyB) - GUARD, pymax = fmaxf(pyA,pyB) + GUARD;
        int mnx = min(max((int)floorf(pxmin), 0), NW-1);
        int mxx = min(max((int)floorf(pxmax) + 1, 0), NW-1);
        int mny = min(max((int)floorf(pymin), 0), NH-1);
        int mxy = min(max((int)floorf(pymax) + 1, 0), NH-1);
        int bw = mxx - mnx + 1;
        int bh = mxy - mny + 1;
        mnxa[vv] = mnx; mnya[vv] = mny; bwa[vv] = bw;
        Ua[vv] = ok ? (bw * bh) : (QMAX + 1);
    }

    float sv[2], tv[2];

    #pragma unroll
    for (int vv = 0; vv < 2; ++vv) {
        int v = hi + 2*vv;
        int vb = v*NB + b;
        float w00 = w00a[vv], w01 = w01a[vv], w10 = w10a[vv], w11 = w11a[vv];
        int xc0 = xc0a[vv], xc1 = xc1a[vv], yc0 = yc0a[vv], yc1 = yc1a[vv];
        int mnx = mnxa[vv], mny = mnya[vv], bw = bwa[vv];
        int U = Ua[vv];

        const float4* rr = (const float4*)(refT + ((size_t)vb*HW + h*NW + w)*NC);
        float s = 0.f, t = 0.f;

        if (U <= QMAX) {
            float4 rf0 = rr[j0];
            float4 rf1 = rr[j0+1];
            int bw8 = bw * 8;
            int NE2 = ((U) * 8) >> 1;          // U = bw*bh here, NE = bh*bw8
            unsigned int M = (unsigned int)((1u<<22) / (unsigned int)bw8) + 1u;
            int rowstride = NW*NC;
            const float* base = srcT + ((size_t)vb*HW + (size_t)mny*NW + mnx)*NC;
            for (int m = sub; m < NE2; m += 32) {
                int n0 = 2*m;
                int row = (int)(((unsigned int)n0 * M) >> 22);
                int col = n0 - row*bw8;
                const float4* fp = (const float4*)(base + row*rowstride + col*4);
                float4 f0 = fp[0], f1 = fp[1];
                float dv0 = f0.x*rf0.x;
                dv0 = fmaf(f0.y, rf0.y, dv0);
                dv0 = fmaf(f0.z, rf0.z, dv0);
                dv0 = fmaf(f0.w, rf0.w, dv0);
                float dv1 = f1.x*rf1.x;
                dv1 = fmaf(f1.y, rf1.y, dv1);
                dv1 = fmaf(f1.z, rf1.z, dv1);
                dv1 = fmaf(f1.w, rf1.w, dv1);
                *(float2*)&Dh[n0] = make_float2(dv0, dv1);
            }
            __builtin_amdgcn_wave_barrier();

            #pragma unroll
            for (int k = 0; k < 2; ++k) {
                int q = sub + k*32;
                if (q < U) {
                    const float4* dp = (const float4*)&Dh[q*8];
                    float4 a = dp[0], c = dp[1];
                    float S = a.x;  S += a.y;  S += a.z;  S += a.w;
                    S += c.x;  S += c.y;  S += c.z;  S += c.w;
                    float T = wr[0]*a.x;
                    T = fmaf(wr[1], a.y, T);
                    T = fmaf(wr[2], a.z, T);
                    T = fmaf(wr[3], a.w, T);
                    T = fmaf(wr[4], c.x, T);
                    T = fmaf(wr[5], c.y, T);
                    T = fmaf(wr[6], c.z, T);
                    T = fmaf(wr[7], c.w, T);
                    Sh[q] = make_float2(S, T);
                }
            }
            __builtin_amdgcn_wave_barrier();

            int t00 = (yc0 - mny)*bw + (xc0 - mnx);
            int t01 = (yc0 - mny)*bw + (xc1 - mnx);
            int t10 = (yc1 - mny)*bw + (xc0 - mnx);
            int t11 = (yc1 - mny)*bw + (xc1 - mnx);
            float2 v00 = Sh[t00];
            float2 v01 = Sh[t01];
            float2 v10 = Sh[t10];
            float2 v11 = Sh[t11];
            s = 0.25f*(w00*v00.x + w01*v01.x + w10*v10.x + w11*v11.x);
            t = 0.25f*(w00*v00.y + w01*v01.y + w10*v10.y + w11*v11.y);
        } else {
            int i00 = yc0*NW+xc0, i01 = yc0*NW+xc1;
            int i10 = yc1*NW+xc0, i11 = yc1*NW+xc1;
            const float4* s00 = (const float4*)(srcT + ((size_t)vb*HW + i00)*NC);
            const float4* s01 = (const float4*)(srcT + ((size_t)vb*HW + i01)*NC);
            const float4* s10 = (const float4*)(srcT + ((size_t)vb*HW + i10)*NC);
            const float4* s11 = (const float4*)(srcT + ((size_t)vb*HW + i11)*NC);
            #pragma unroll
            for (int j = 0; j < NG; ++j) {
                float4 a00 = s00[j], a01 = s01[j], a10 = s10[j], a11 = s11[j];
                float4 rf  = rr[j];
                float acc = 0.f;
                float f0 = w00*a00.x + w01*a01.x + w10*a10.x + w11*a11.x;
                acc += f0*rf.x;
                float f1 = w00*a00.y + w01*a01.y + w10*a10.y + w11*a11.y;
                acc += f1*rf.y;
                float f2 = w00*a00.z + w01*a01.z + w10*a10.z + w11*a11.z;
                acc += f2*rf.z;
                float f3 = w00*a00.w + w01*a01.w + w10*a10.w + w11*a11.w;
                acc += f3*rf.w;
                float cf = 0.25f*acc;
                s += cf;
                t += cf*wr[j];
            }
        }
        sv[vv] = s; tv[vv] = t;
    }

    // ---- per-view softmax over depths within the half ----
    float mv0 = sv[0], mv1 = sv[1];
    #pragma unroll
    for (int mask = 1; mask < 32; mask <<= 1) {
        mv0 = fmaxf(mv0, __shfl_xor(mv0, mask, 32));
        mv1 = fmaxf(mv1, __shfl_xor(mv1, mask, 32));
    }
    float Z0 = __expf(sv[0] - mv0);
    float Z1 = __expf(sv[1] - mv1);
    #pragma unroll
    for (int mask = 1; mask < 32; mask <<= 1) {
        Z0 += __shfl_xor(Z0, mask, 32);
        Z1 += __shfl_xor(Z1, mask, 32);
    }
    float cwA0 = RCPF(Z0);
    float cwA1 = RCPF(Z1);

    float cwB0 = __shfl_xor(cwA0, 32, 64);
    float cwB1 = __shfl_xor(cwA1, 32, 64);
    float tB0  = __shfl_xor(tv[0], 32, 64);
    float tB1  = __shfl_xor(tv[1], 32, 64);

    float cwv[NV], tvv[NV];
    if (hi == 0) {
        cwv[0] = cwA0; tvv[0] = tv[0];
        cwv[1] = cwB0; tvv[1] = tB0;
        cwv[2] = cwA1; tvv[2] = tv[1];
        cwv[3] = cwB1; tvv[3] = tB1;
    } else {
        cwv[0] = cwB0; tvv[0] = tB0;
        cwv[1] = cwA0; tvv[1] = tv[0];
        cwv[2] = cwB1; tvv[2] = tB1;
        cwv[3] = cwA1; tvv[3] = tv[1];
    }
    float logacc = 0.f;
    float cwsum  = 1e-8f;
    #pragma unroll
    for (int v = 0; v < NV; ++v) {
        logacc += cwv[v]*tvv[v];
        cwsum  += cwv[v];
    }

    float logit = logacc / (cwsum + 1e-7f);
    float m2 = logit;
    #pragma unroll
    for (int mask = 1; mask < 32; mask <<= 1)
        m2 = fmaxf(m2, __shfl_xor(m2, mask, 32));
    float e2 = __expf(logit - m2);
    float Z2 = e2;
    #pragma unroll
    for (int mask = 1; mask < 32; mask <<= 1)
        Z2 += __shfl_xor(Z2, mask, 32);
    float aw = e2 / Z2;

    float bv2 = aw; int bi = d;
    #pragma unroll
    for (int mask = 1; mask < 32; mask <<= 1) {
        float ov = __shfl_xor(bv2, mask, 32);
        int   oi = __shfl_xor(bi, mask, 32);
        if (ov > bv2 || (ov == bv2 && oi < bi)) { bv2 = ov; bi = oi; }
    }
    float dsel = __shfl(depth, bi, 32);

    if (hi == 0) {
        out[NPIX + ((b*ND + d)*NH + h)*NW + w] = aw;
        if (d == 0) out[p] = dsel;
    }
}

// ---------------------------------------------------------------------------
// Fallback (original layout, f64 geometry) if ws tiny
// ---------------------------------------------------------------------------
__global__ void proj_setup_kernel(const float* __restrict__ proj,
                                  float* __restrict__ pw) {
    int t = blockIdx.x * blockDim.x + threadIdx.x;
    if (t >= NB * NV) return;
    int b = t / NV, v = t % NV;
    const float* Eref = proj + ((b*(NV+1) + 0)*2 + 0)*16;
    const float* Kref = proj + ((b*(NV+1) + 0)*2 + 1)*16;
    const float* Esrc = proj + ((b*(NV+1) + (v+1))*2 + 0)*16;
    const float* Ksrc = proj + ((b*(NV+1) + (v+1))*2 + 1)*16;
    float Mr[12], Ms[12];
    for (int i = 0; i < 3; ++i)
        for (int j = 0; j < 4; ++j) {
            float sr = 0.f, ss = 0.f;
            for (int k = 0; k < 3; ++k) {
                sr += Kref[i*4+k] * Eref[k*4+j];
                ss += Ksrc[i*4+k] * Esrc[k*4+j];
            }
            Mr[i*4+j] = sr; Ms[i*4+j] = ss;
        }
    double A[9], a[3];
    for (int i = 0; i < 3; ++i) {
        for (int j = 0; j < 3; ++j) A[i*3+j] = (double)Mr[i*4+j];
        a[i] = (double)Mr[i*4+3];
    }
    double c00 = A[4]*A[8]-A[5]*A[7];
    double c01 = A[5]*A[6]-A[3]*A[8];
    double c02 = A[3]*A[7]-A[4]*A[6];
    double det = A[0]*c00 + A[1]*c01 + A[2]*c02;
    double id  = 1.0/det;
    double Ai[9];
    Ai[0]=c00*id;                 Ai[1]=(A[2]*A[7]-A[1]*A[8])*id; Ai[2]=(A[1]*A[5]-A[2]*A[4])*id;
    Ai[3]=c01*id;                 Ai[4]=(A[0]*A[8]-A[2]*A[6])*id; Ai[5]=(A[2]*A[3]-A[0]*A[5])*id;
    Ai[6]=c02*id;                 Ai[7]=(A[1]*A[6]-A[0]*A[7])*id; Ai[8]=(A[0]*A[4]-A[1]*A[3])*id;
    double R[9], T[3];
    for (int i = 0; i < 3; ++i)
        for (int j = 0; j < 3; ++j) {
            double s = 0.0;
            for (int k = 0; k < 3; ++k) s += (double)Ms[i*4+k] * Ai[k*3+j];
            R[i*3+j] = s;
        }
    for (int i = 0; i < 3; ++i) {
        double s = (double)Ms[i*4+3];
        for (int k = 0; k < 3; ++k) s -= R[i*3+k]*a[k];
        T[i] = s;
    }
    float* o = pw + (b*NV + v)*12;
    for (int i = 0; i < 9; ++i) o[i]   = (float)R[i];
    for (int i = 0; i < 3; ++i) o[9+i] = (float)T[i];
}

__global__ __launch_bounds__(256) void mvs_kernel(
    const float* __restrict__ ref_feats,
    const float* __restrict__ src_feats,
    const float* __restrict__ depth_hypo,
    const float* __restrict__ w_reg,
    const float* __restrict__ pw,
    float* __restrict__ out)
{
    int tid = blockIdx.x * 256 + threadIdx.x;
    int d = threadIdx.x & 31;
    int p = tid >> 5;
    if (p >= NPIX) return;
    int w = p % NW;
    int h = (p / NW) % NH;
    int b = p / (NW*NH);
    float xf = (float)w, yf = (float)h;
    float depth = depth_hypo[((b*ND + d)*NH + h)*NW + w];
    float wr[NG];
    #pragma unroll
    for (int g = 0; g < NG; ++g) wr[g] = w_reg[g];
    float logacc = 0.f;
    float cwsum  = 1e-8f;
    for (int v = 0; v < NV; ++v) {
        const float* RT = pw + (b*NV + v)*12;
        double dd  = (double)depth;
        double px_ = ((double)RT[0]*(double)xf + (double)RT[1]*(double)yf + (double)RT[2])*dd + (double)RT[9];
        double py_ = ((double)RT[3]*(double)xf + (double)RT[4]*(double)yf + (double)RT[5])*dd + (double)RT[10];
        double pz_ = ((double)RT[6]*(double)xf + (double)RT[7]*(double)yf + (double)RT[8])*dd + (double)RT[11];
        if (pz_ == 0.0) pz_ = 1e-9;
        double iz = 1.0/pz_;
        double pxd = px_*iz, pyd = py_*iz;
        double x0d = floor(pxd), y0d = floor(pyd);
        int x0i = (int)x0d, y0i = (int)y0d;
        int x1i = x0i + 1,  y1i = y0i + 1;
        float wx = (float)(pxd - x0d), wy = (float)(pyd - y0d);
        float vx0 = (x0i >= 0 && x0i < NW) ? 1.f : 0.f;
        float vx1 = (x1i >= 0 && x1i < NW) ? 1.f : 0.f;
        float vy0 = (y0i >= 0 && y0i < NH) ? 1.f : 0.f;
        float vy1 = (y1i >= 0 && y1i < NH) ? 1.f : 0.f;
        float w00 = (1.f-wx)*(1.f-wy) * vx0*vy0;
        float w01 = wx*(1.f-wy)       * vx1*vy0;
        float w10 = (1.f-wx)*wy       * vx0*vy1;
        float w11 = wx*wy             * vx1*vy1;
        int xc0 = min(max(x0i,0),NW-1), xc1 = min(max(x1i,0),NW-1);
        int yc0 = min(max(y0i,0),NH-1), yc1 = min(max(y1i,0),NH-1);
        int i00 = yc0*NW+xc0, i01 = yc0*NW+xc1;
        int i10 = yc1*NW+xc0, i11 = yc1*NW+xc1;
        const float* sb = src_feats + ((v*NB + b)*NC)*HW;
        const float* rb = ref_feats + ((v*NB + b)*NC)*HW + h*NW + w;
        float acc[NG];
        #pragma unroll
        for (int g = 0; g < NG; ++g) acc[g] = 0.f;
        #pragma unroll
        for (int c = 0; c < NC; ++c) {
            const float* scp = sb + c*HW;
            float f = w00*scp[i00] + w01*scp[i01] + w10*scp[i10] + w11*scp[i11];
            acc[c>>2] += f * rb[c*HW];
        }
        float s = 0.f, t = 0.f;
        #pragma unroll
        for (int g = 0; g < NG; ++g) {
            float cf = 0.25f*acc[g];
            s += cf;
            t += cf*wr[g];
        }
        float m = s;
        #pragma unroll
        for (int mask = 1; mask < 32; mask <<= 1)
            m = fmaxf(m, __shfl_xor(m, mask, 32));
        float e = expf(s - m);
        float Z = e;
        #pragma unroll
        for (int mask = 1; mask < 32; mask <<= 1)
            Z += __shfl_xor(Z, mask, 32);
        float cw = 1.f / Z;
        logacc += cw * t;
        cwsum  += cw;
    }
    float logit = logacc / (cwsum + 1e-7f);
    float m2 = logit;
    #pragma unroll
    for (int mask = 1; mask < 32; mask <<= 1)
        m2 = fmaxf(m2, __shfl_xor(m2, mask, 32));
    float e2 = expf(logit - m2);
    float Z2 = e2;
    #pragma unroll
    for (int mask = 1; mask < 32; mask <<= 1)
        Z2 += __shfl_xor(Z2, mask, 32);
    float aw = e2 / Z2;
    out[NPIX + ((b*ND + d)*NH + h)*NW + w] = aw;
    float bv = aw; int bi = d;
    #pragma unroll
    for (int mask = 1; mask < 32; mask <<= 1) {
        float ov = __shfl_xor(bv, mask, 32);
        int   oi = __shfl_xor(bi, mask, 32);
        if (ov > bv || (ov == bv && oi < bi)) { bv = ov; bi = oi; }
    }
    float dsel = __shfl(depth, bi, 32);
    if (d == 0) out[p] = dsel;
}

extern "C" void kernel_launch(void* const* d_in, const int* in_sizes, int n_in,
                              void* d_out, int out_size, void* d_ws, size_t ws_size,
                              hipStream_t stream) {
    const float* ref_feats  = (const float*)d_in[0];
    const float* src_feats  = (const float*)d_in[1];
    const float* proj       = (const float*)d_in[2];
    const float* depth_hypo = (const float*)d_in[3];
    const float* w_reg      = (const float*)d_in[4];
    float* out = (float*)d_out;

    size_t featB = (size_t)FEATSZ*sizeof(float);
    size_t needG = 2*featB + 96*sizeof(float);

    if (ws_size >= needG) {
        char* base = (char*)d_ws;
        float* srcT = (float*)base;                 base += featB;
        float* refT = (float*)base;                 base += featB;
        float* pw = (float*)base;
        hipLaunchKernelGGL(prep_kernel, dim3(2*TGRID + 1), dim3(256), 0, stream,
                           src_feats, ref_feats, proj, srcT, refT, pw);
        hipLaunchKernelGGL(mvs_kernel_g, dim3((NPIX*64)/256), dim3(256), 0, stream,
                           refT, srcT, depth_hypo, w_reg, pw, out);
    } else {
        float* pw = (float*)d_ws;
        hipLaunchKernelGGL(proj_setup_kernel, dim3(1), dim3(64), 0, stream, proj, pw);
        hipLaunchKernelGGL(mvs_kernel, dim3((NPIX*ND)/256), dim3(256), 0, stream,
                           ref_feats, src_feats, depth_hypo, w_reg, pw, out);
    }
}

// Round 21
// 96.490 us; speedup vs baseline: 1.1545x; 1.1545x over previous
//
#include <hip/hip_runtime.h>
#include <math.h>

#define NV 4
#define NB 2
#define NC 32
#define ND 32
#define NH 128
#define NW 160
#define NG 8
#define HW (NH*NW)
#define NPIX (NB*NH*NW)
#define FEATSZ (NV*NB*HW*NC)
#define QMAX 60                // window slots; LDS = 15360 (Dsc) + 3840 (STl) = 19200 B -> 8 blk/CU
#define TBLK (HW/64)
#define TGRID (TBLK*NV*NB)
#define GUARD 0.01f

#define RCPF(x) __builtin_amdgcn_rcpf(x)

// ---------------------------------------------------------------------------
// Fused prep: blocks [0,2*TGRID) transpose src/ref (vectorized float4 both
// sides); block 2*TGRID computes P = K3@E_src @ inv(K3@E_ref) (f64 inverse).
// ---------------------------------------------------------------------------
__global__ __launch_bounds__(256) void prep_kernel(
    const float* __restrict__ src_feats,
    const float* __restrict__ ref_feats,
    const float* __restrict__ proj,
    float* __restrict__ srcT,
    float* __restrict__ refT,
    float* __restrict__ pw)
{
    __shared__ float lds[NC][65];
    int bid = blockIdx.x;
    if (bid < 2*TGRID) {
        int which = bid >= TGRID;
        int tb = which ? bid - TGRID : bid;
        const float* in = which ? ref_feats : src_feats;
        float* outp     = which ? refT : srcT;
        int vb = tb / TBLK;
        int hwbase = (tb % TBLK) * 64;
        int t = threadIdx.x;
        #pragma unroll
        for (int r = 0; r < 2; ++r) {
            int c   = (t >> 4) + r*16;
            int hw4 = (t & 15) * 4;
            float4 f = *(const float4*)&in[(vb*NC + c)*HW + hwbase + hw4];
            lds[c][hw4+0] = f.x;
            lds[c][hw4+1] = f.y;
            lds[c][hw4+2] = f.z;
            lds[c][hw4+3] = f.w;
        }
        __syncthreads();
        {
            int hw = t >> 2;
            int c0 = (t & 3) * 8;
            float o[8];
            #pragma unroll
            for (int k = 0; k < 8; ++k) o[k] = lds[c0+k][hw];
            float* dst = &outp[((size_t)vb*HW + hwbase + hw)*NC + c0];
            *(float4*)(dst)     = make_float4(o[0],o[1],o[2],o[3]);
            *(float4*)(dst + 4) = make_float4(o[4],o[5],o[6],o[7]);
        }
        return;
    }
    // ---- proj block ----
    int t = threadIdx.x;
    if (t >= NB * NV) return;
    int b = t / NV, v = t % NV;
    const float* Eref = proj + ((b*(NV+1) + 0)*2 + 0)*16;
    const float* Kref = proj + ((b*(NV+1) + 0)*2 + 1)*16;
    const float* Esrc = proj + ((b*(NV+1) + (v+1))*2 + 0)*16;
    const float* Ksrc = proj + ((b*(NV+1) + (v+1))*2 + 1)*16;
    float Mr[12], Ms[12];
    for (int i = 0; i < 3; ++i)
        for (int j = 0; j < 4; ++j) {
            float sr = 0.f, ss = 0.f;
            for (int k = 0; k < 3; ++k) {
                sr += Kref[i*4+k] * Eref[k*4+j];
                ss += Ksrc[i*4+k] * Esrc[k*4+j];
            }
            Mr[i*4+j] = sr; Ms[i*4+j] = ss;
        }
    double A[9], a[3];
    for (int i = 0; i < 3; ++i) {
        for (int j = 0; j < 3; ++j) A[i*3+j] = (double)Mr[i*4+j];
        a[i] = (double)Mr[i*4+3];
    }
    double c00 = A[4]*A[8]-A[5]*A[7];
    double c01 = A[5]*A[6]-A[3]*A[8];
    double c02 = A[3]*A[7]-A[4]*A[6];
    double det = A[0]*c00 + A[1]*c01 + A[2]*c02;
    double id  = 1.0/det;
    double Ai[9];
    Ai[0]=c00*id;                 Ai[1]=(A[2]*A[7]-A[1]*A[8])*id; Ai[2]=(A[1]*A[5]-A[2]*A[4])*id;
    Ai[3]=c01*id;                 Ai[4]=(A[0]*A[8]-A[2]*A[6])*id; Ai[5]=(A[2]*A[3]-A[0]*A[5])*id;
    Ai[6]=c02*id;                 Ai[7]=(A[1]*A[6]-A[0]*A[7])*id; Ai[8]=(A[0]*A[4]-A[1]*A[3])*id;
    double R[9], T[3];
    for (int i = 0; i < 3; ++i)
        for (int j = 0; j < 3; ++j) {
            double s = 0.0;
            for (int k = 0; k < 3; ++k) s += (double)Ms[i*4+k] * Ai[k*3+j];
            R[i*3+j] = s;
        }
    for (int i = 0; i < 3; ++i) {
        double s = (double)Ms[i*4+3];
        for (int k = 0; k < 3; ++k) s -= R[i*3+k]*a[k];
        T[i] = s;
    }
    float* o = pw + (b*NV + v)*12;
    for (int i = 0; i < 9; ++i) o[i]   = (float)R[i];
    for (int i = 0; i < 3; ++i) o[9+i] = (float)T[i];
}

// ---------------------------------------------------------------------------
// Main: wave = pixel; half hi owns views {hi, hi+2}. f32 geometry (v_rcp),
// endpoint bbox, PAIRED flattened staging (lane = 2 consecutive elements,
// one 32B region, fixed chunk pair j0=(2*sub)&7, ds_write_b64), S/T
// compaction, __expf softmax. (R18 structure — final.)
// ---------------------------------------------------------------------------
__global__ __launch_bounds__(256) void mvs_kernel_g(
    const float* __restrict__ refT,
    const float* __restrict__ srcT,
    const float* __restrict__ depth_hypo,
    const float* __restrict__ w_reg,
    const float* __restrict__ pw,
    float* __restrict__ out)
{
    __shared__ float  Dsc[8][QMAX*8];   // 15360 B
    __shared__ float2 STl[8][QMAX];     // 3840 B

    int tid = blockIdx.x * 256 + threadIdx.x;
    int lane = threadIdx.x & 63;
    int d  = lane & 31;
    int hi = lane >> 5;
    int p  = tid >> 6;
    if (p >= NPIX) return;
    int hslot = threadIdx.x >> 5;
    float*  Dh = &Dsc[hslot][0];
    float2* Sh = &STl[hslot][0];
    int sub = lane & 31;
    int j0  = (2*sub) & 7;      // fixed chunk pair for paired staging

    int w = p % NW;
    int h = (p / NW) % NH;
    int b = p / (NW*NH);
    float xf = (float)w, yf = (float)h;
    float depth = depth_hypo[((b*ND + d)*NH + h)*NW + w];

    float dep0  = __shfl(depth, 0, 32);
    float dep31 = __shfl(depth, 31, 32);

    float wr[NG];
    #pragma unroll
    for (int g = 0; g < NG; ++g) wr[g] = w_reg[g];

    float sv[2], tv[2];

    #pragma unroll
    for (int vv = 0; vv < 2; ++vv) {
        int v = hi + 2*vv;
        const float* RT = pw + (b*NV + v)*12;

        // ---- f32 geometry ----
        float rx = RT[0]*xf + RT[1]*yf + RT[2];
        float ry = RT[3]*xf + RT[4]*yf + RT[5];
        float rz = RT[6]*xf + RT[7]*yf + RT[8];
        float px_ = rx*depth + RT[9];
        float py_ = ry*depth + RT[10];
        float pz_ = rz*depth + RT[11];
        if (pz_ == 0.f) pz_ = 1e-9f;
        float iz = RCPF(pz_);
        float px = px_*iz, py = py_*iz;
        float fx0 = floorf(px), fy0 = floorf(py);
        int x0i = (int)fx0, y0i = (int)fy0;
        int x1i = x0i + 1, y1i = y0i + 1;
        float wx = px - fx0, wy = py - fy0;

        float vx0 = (x0i >= 0 && x0i < NW) ? 1.f : 0.f;
        float vx1 = (x1i >= 0 && x1i < NW) ? 1.f : 0.f;
        float vy0 = (y0i >= 0 && y0i < NH) ? 1.f : 0.f;
        float vy1 = (y1i >= 0 && y1i < NH) ? 1.f : 0.f;
        float w00 = (1.f-wx)*(1.f-wy) * vx0*vy0;
        float w01 = wx*(1.f-wy)       * vx1*vy0;
        float w10 = (1.f-wx)*wy       * vx0*vy1;
        float w11 = wx*wy             * vx1*vy1;
        int xc0 = min(max(x0i,0),NW-1), xc1 = min(max(x1i,0),NW-1);
        int yc0 = min(max(y0i,0),NH-1), yc1 = min(max(y1i,0),NH-1);
        int vb = v*NB + b;

        // ---- endpoint-projection bbox ----
        float pzA = rz*dep0  + RT[11];
        float pzB = rz*dep31 + RT[11];
        if (pzA == 0.f) pzA = 1e-9f;
        if (pzB == 0.f) pzB = 1e-9f;
        bool ok = (pzA > 0.f) == (pzB > 0.f);
        float izA = RCPF(pzA), izB = RCPF(pzB);
        float pxA = (rx*dep0  + RT[9])*izA,  pyA = (ry*dep0  + RT[10])*izA;
        float pxB = (rx*dep31 + RT[9])*izB,  pyB = (ry*dep31 + RT[10])*izB;
        float pxmin = fminf(pxA,pxB) - GUARD, pxmax = fmaxf(pxA,pxB) + GUARD;
        float pymin = fminf(pyA,pyB) - GUARD, pymax = fmaxf(pyA,pyB) + GUARD;
        int mnx = min(max((int)floorf(pxmin), 0), NW-1);
        int mxx = min(max((int)floorf(pxmax) + 1, 0), NW-1);
        int mny = min(max((int)floorf(pymin), 0), NH-1);
        int mxy = min(max((int)floorf(pymax) + 1, 0), NH-1);
        int bw = mxx - mnx + 1;
        int bh = mxy - mny + 1;
        int U  = ok ? (bw * bh) : (QMAX + 1);

        const float4* rr = (const float4*)(refT + ((size_t)vb*HW + h*NW + w)*NC);
        float s = 0.f, t = 0.f;

        if (U <= QMAX) {
            float4 rf0 = rr[j0];
            float4 rf1 = rr[j0+1];
            // ---- phase 1: PAIRED flattened staging (2 elements / lane / iter) ----
            int bw8 = bw * 8;
            int NE2 = (bh * bw8) >> 1;        // element pairs (bw8 even -> NE even)
            unsigned int M = (unsigned int)((1u<<22) / (unsigned int)bw8) + 1u;
            int rowstride = NW*NC;
            const float* base = srcT + ((size_t)vb*HW + (size_t)mny*NW + mnx)*NC;
            for (int m = sub; m < NE2; m += 32) {
                int n0 = 2*m;
                int row = (int)(((unsigned int)n0 * M) >> 22);
                int col = n0 - row*bw8;
                const float4* fp = (const float4*)(base + row*rowstride + col*4);
                float4 f0 = fp[0], f1 = fp[1];
                float dv0 = f0.x*rf0.x;
                dv0 = fmaf(f0.y, rf0.y, dv0);
                dv0 = fmaf(f0.z, rf0.z, dv0);
                dv0 = fmaf(f0.w, rf0.w, dv0);
                float dv1 = f1.x*rf1.x;
                dv1 = fmaf(f1.y, rf1.y, dv1);
                dv1 = fmaf(f1.z, rf1.z, dv1);
                dv1 = fmaf(f1.w, rf1.w, dv1);
                *(float2*)&Dh[n0] = make_float2(dv0, dv1);
            }
            __builtin_amdgcn_wave_barrier();

            // ---- phase 2: compact 8 djs -> (S,T) per q ----
            #pragma unroll
            for (int k = 0; k < 2; ++k) {
                int q = sub + k*32;
                if (q < U) {
                    const float4* dp = (const float4*)&Dh[q*8];
                    float4 a = dp[0], c = dp[1];
                    float S = a.x;  S += a.y;  S += a.z;  S += a.w;
                    S += c.x;  S += c.y;  S += c.z;  S += c.w;
                    float T = wr[0]*a.x;
                    T = fmaf(wr[1], a.y, T);
                    T = fmaf(wr[2], a.z, T);
                    T = fmaf(wr[3], a.w, T);
                    T = fmaf(wr[4], c.x, T);
                    T = fmaf(wr[5], c.y, T);
                    T = fmaf(wr[6], c.z, T);
                    T = fmaf(wr[7], c.w, T);
                    Sh[q] = make_float2(S, T);
                }
            }
            __builtin_amdgcn_wave_barrier();

            // ---- taps ----
            int t00 = (yc0 - mny)*bw + (xc0 - mnx);
            int t01 = (yc0 - mny)*bw + (xc1 - mnx);
            int t10 = (yc1 - mny)*bw + (xc0 - mnx);
            int t11 = (yc1 - mny)*bw + (xc1 - mnx);
            float2 v00 = Sh[t00];
            float2 v01 = Sh[t01];
            float2 v10 = Sh[t10];
            float2 v11 = Sh[t11];
            s = 0.25f*(w00*v00.x + w01*v01.x + w10*v10.x + w11*v11.x);
            t = 0.25f*(w00*v00.y + w01*v01.y + w10*v10.y + w11*v11.y);
        } else {
            int i00 = yc0*NW+xc0, i01 = yc0*NW+xc1;
            int i10 = yc1*NW+xc0, i11 = yc1*NW+xc1;
            const float4* s00 = (const float4*)(srcT + ((size_t)vb*HW + i00)*NC);
            const float4* s01 = (const float4*)(srcT + ((size_t)vb*HW + i01)*NC);
            const float4* s10 = (const float4*)(srcT + ((size_t)vb*HW + i10)*NC);
            const float4* s11 = (const float4*)(srcT + ((size_t)vb*HW + i11)*NC);
            #pragma unroll
            for (int j = 0; j < NG; ++j) {
                float4 a00 = s00[j], a01 = s01[j], a10 = s10[j], a11 = s11[j];
                float4 rf  = rr[j];
                float acc = 0.f;
                float f0 = w00*a00.x + w01*a01.x + w10*a10.x + w11*a11.x;
                acc += f0*rf.x;
                float f1 = w00*a00.y + w01*a01.y + w10*a10.y + w11*a11.y;
                acc += f1*rf.y;
                float f2 = w00*a00.z + w01*a01.z + w10*a10.z + w11*a11.z;
                acc += f2*rf.z;
                float f3 = w00*a00.w + w01*a01.w + w10*a10.w + w11*a11.w;
                acc += f3*rf.w;
                float cf = 0.25f*acc;
                s += cf;
                t += cf*wr[j];
            }
        }
        sv[vv] = s; tv[vv] = t;
    }

    // ---- per-view softmax over depths within the half ----
    float mv0 = sv[0], mv1 = sv[1];
    #pragma unroll
    for (int mask = 1; mask < 32; mask <<= 1) {
        mv0 = fmaxf(mv0, __shfl_xor(mv0, mask, 32));
        mv1 = fmaxf(mv1, __shfl_xor(mv1, mask, 32));
    }
    float Z0 = __expf(sv[0] - mv0);
    float Z1 = __expf(sv[1] - mv1);
    #pragma unroll
    for (int mask = 1; mask < 32; mask <<= 1) {
        Z0 += __shfl_xor(Z0, mask, 32);
        Z1 += __shfl_xor(Z1, mask, 32);
    }
    float cwA0 = RCPF(Z0);
    float cwA1 = RCPF(Z1);

    float cwB0 = __shfl_xor(cwA0, 32, 64);
    float cwB1 = __shfl_xor(cwA1, 32, 64);
    float tB0  = __shfl_xor(tv[0], 32, 64);
    float tB1  = __shfl_xor(tv[1], 32, 64);

    float cwv[NV], tvv[NV];
    if (hi == 0) {
        cwv[0] = cwA0; tvv[0] = tv[0];
        cwv[1] = cwB0; tvv[1] = tB0;
        cwv[2] = cwA1; tvv[2] = tv[1];
        cwv[3] = cwB1; tvv[3] = tB1;
    } else {
        cwv[0] = cwB0; tvv[0] = tB0;
        cwv[1] = cwA0; tvv[1] = tv[0];
        cwv[2] = cwB1; tvv[2] = tB1;
        cwv[3] = cwA1; tvv[3] = tv[1];
    }
    float logacc = 0.f;
    float cwsum  = 1e-8f;
    #pragma unroll
    for (int v = 0; v < NV; ++v) {
        logacc += cwv[v]*tvv[v];
        cwsum  += cwv[v];
    }

    float logit = logacc / (cwsum + 1e-7f);
    float m2 = logit;
    #pragma unroll
    for (int mask = 1; mask < 32; mask <<= 1)
        m2 = fmaxf(m2, __shfl_xor(m2, mask, 32));
    float e2 = __expf(logit - m2);
    float Z2 = e2;
    #pragma unroll
    for (int mask = 1; mask < 32; mask <<= 1)
        Z2 += __shfl_xor(Z2, mask, 32);
    float aw = e2 / Z2;

    float bv2 = aw; int bi = d;
    #pragma unroll
    for (int mask = 1; mask < 32; mask <<= 1) {
        float ov = __shfl_xor(bv2, mask, 32);
        int   oi = __shfl_xor(bi, mask, 32);
        if (ov > bv2 || (ov == bv2 && oi < bi)) { bv2 = ov; bi = oi; }
    }
    float dsel = __shfl(depth, bi, 32);

    if (hi == 0) {
        out[NPIX + ((b*ND + d)*NH + h)*NW + w] = aw;
        if (d == 0) out[p] = dsel;
    }
}

// ---------------------------------------------------------------------------
// Fallback (original layout, f64 geometry) if ws tiny
// ---------------------------------------------------------------------------
__global__ void proj_setup_kernel(const float* __restrict__ proj,
                                  float* __restrict__ pw) {
    int t = blockIdx.x * blockDim.x + threadIdx.x;
    if (t >= NB * NV) return;
    int b = t / NV, v = t % NV;
    const float* Eref = proj + ((b*(NV+1) + 0)*2 + 0)*16;
    const float* Kref = proj + ((b*(NV+1) + 0)*2 + 1)*16;
    const float* Esrc = proj + ((b*(NV+1) + (v+1))*2 + 0)*16;
    const float* Ksrc = proj + ((b*(NV+1) + (v+1))*2 + 1)*16;
    float Mr[12], Ms[12];
    for (int i = 0; i < 3; ++i)
        for (int j = 0; j < 4; ++j) {
            float sr = 0.f, ss = 0.f;
            for (int k = 0; k < 3; ++k) {
                sr += Kref[i*4+k] * Eref[k*4+j];
                ss += Ksrc[i*4+k] * Esrc[k*4+j];
            }
            Mr[i*4+j] = sr; Ms[i*4+j] = ss;
        }
    double A[9], a[3];
    for (int i = 0; i < 3; ++i) {
        for (int j = 0; j < 3; ++j) A[i*3+j] = (double)Mr[i*4+j];
        a[i] = (double)Mr[i*4+3];
    }
    double c00 = A[4]*A[8]-A[5]*A[7];
    double c01 = A[5]*A[6]-A[3]*A[8];
    double c02 = A[3]*A[7]-A[4]*A[6];
    double det = A[0]*c00 + A[1]*c01 + A[2]*c02;
    double id  = 1.0/det;
    double Ai[9];
    Ai[0]=c00*id;                 Ai[1]=(A[2]*A[7]-A[1]*A[8])*id; Ai[2]=(A[1]*A[5]-A[2]*A[4])*id;
    Ai[3]=c01*id;                 Ai[4]=(A[0]*A[8]-A[2]*A[6])*id; Ai[5]=(A[2]*A[3]-A[0]*A[5])*id;
    Ai[6]=c02*id;                 Ai[7]=(A[1]*A[6]-A[0]*A[7])*id; Ai[8]=(A[0]*A[4]-A[1]*A[3])*id;
    double R[9], T[3];
    for (int i = 0; i < 3; ++i)
        for (int j = 0; j < 3; ++j) {
            double s = 0.0;
            for (int k = 0; k < 3; ++k) s += (double)Ms[i*4+k] * Ai[k*3+j];
            R[i*3+j] = s;
        }
    for (int i = 0; i < 3; ++i) {
        double s = (double)Ms[i*4+3];
        for (int k = 0; k < 3; ++k) s -= R[i*3+k]*a[k];
        T[i] = s;
    }
    float* o = pw + (b*NV + v)*12;
    for (int i = 0; i < 9; ++i) o[i]   = (float)R[i];
    for (int i = 0; i < 3; ++i) o[9+i] = (float)T[i];
}

__global__ __launch_bounds__(256) void mvs_kernel(
    const float* __restrict__ ref_feats,
    const float* __restrict__ src_feats,
    const float* __restrict__ depth_hypo,
    const float* __restrict__ w_reg,
    const float* __restrict__ pw,
    float* __restrict__ out)
{
    int tid = blockIdx.x * 256 + threadIdx.x;
    int d = threadIdx.x & 31;
    int p = tid >> 5;
    if (p >= NPIX) return;
    int w = p % NW;
    int h = (p / NW) % NH;
    int b = p / (NW*NH);
    float xf = (float)w, yf = (float)h;
    float depth = depth_hypo[((b*ND + d)*NH + h)*NW + w];
    float wr[NG];
    #pragma unroll
    for (int g = 0; g < NG; ++g) wr[g] = w_reg[g];
    float logacc = 0.f;
    float cwsum  = 1e-8f;
    for (int v = 0; v < NV; ++v) {
        const float* RT = pw + (b*NV + v)*12;
        double dd  = (double)depth;
        double px_ = ((double)RT[0]*(double)xf + (double)RT[1]*(double)yf + (double)RT[2])*dd + (double)RT[9];
        double py_ = ((double)RT[3]*(double)xf + (double)RT[4]*(double)yf + (double)RT[5])*dd + (double)RT[10];
        double pz_ = ((double)RT[6]*(double)xf + (double)RT[7]*(double)yf + (double)RT[8])*dd + (double)RT[11];
        if (pz_ == 0.0) pz_ = 1e-9;
        double iz = 1.0/pz_;
        double pxd = px_*iz, pyd = py_*iz;
        double x0d = floor(pxd), y0d = floor(pyd);
        int x0i = (int)x0d, y0i = (int)y0d;
        int x1i = x0i + 1,  y1i = y0i + 1;
        float wx = (float)(pxd - x0d), wy = (float)(pyd - y0d);
        float vx0 = (x0i >= 0 && x0i < NW) ? 1.f : 0.f;
        float vx1 = (x1i >= 0 && x1i < NW) ? 1.f : 0.f;
        float vy0 = (y0i >= 0 && y0i < NH) ? 1.f : 0.f;
        float vy1 = (y1i >= 0 && y1i < NH) ? 1.f : 0.f;
        float w00 = (1.f-wx)*(1.f-wy) * vx0*vy0;
        float w01 = wx*(1.f-wy)       * vx1*vy0;
        float w10 = (1.f-wx)*wy       * vx0*vy1;
        float w11 = wx*wy             * vx1*vy1;
        int xc0 = min(max(x0i,0),NW-1), xc1 = min(max(x1i,0),NW-1);
        int yc0 = min(max(y0i,0),NH-1), yc1 = min(max(y1i,0),NH-1);
        int i00 = yc0*NW+xc0, i01 = yc0*NW+xc1;
        int i10 = yc1*NW+xc0, i11 = yc1*NW+xc1;
        const float* sb = src_feats + ((v*NB + b)*NC)*HW;
        const float* rb = ref_feats + ((v*NB + b)*NC)*HW + h*NW + w;
        float acc[NG];
        #pragma unroll
        for (int g = 0; g < NG; ++g) acc[g] = 0.f;
        #pragma unroll
        for (int c = 0; c < NC; ++c) {
            const float* scp = sb + c*HW;
            float f = w00*scp[i00] + w01*scp[i01] + w10*scp[i10] + w11*scp[i11];
            acc[c>>2] += f * rb[c*HW];
        }
        float s = 0.f, t = 0.f;
        #pragma unroll
        for (int g = 0; g < NG; ++g) {
            float cf = 0.25f*acc[g];
            s += cf;
            t += cf*wr[g];
        }
        float m = s;
        #pragma unroll
        for (int mask = 1; mask < 32; mask <<= 1)
            m = fmaxf(m, __shfl_xor(m, mask, 32));
        float e = expf(s - m);
        float Z = e;
        #pragma unroll
        for (int mask = 1; mask < 32; mask <<= 1)
            Z += __shfl_xor(Z, mask, 32);
        float cw = 1.f / Z;
        logacc += cw * t;
        cwsum  += cw;
    }
    float logit = logacc / (cwsum + 1e-7f);
    float m2 = logit;
    #pragma unroll
    for (int mask = 1; mask < 32; mask <<= 1)
        m2 = fmaxf(m2, __shfl_xor(m2, mask, 32));
    float e2 = expf(logit - m2);
    float Z2 = e2;
    #pragma unroll
    for (int mask = 1; mask < 32; mask <<= 1)
        Z2 += __shfl_xor(Z2, mask, 32);
    float aw = e2 / Z2;
    out[NPIX + ((b*ND + d)*NH + h)*NW + w] = aw;
    float bv = aw; int bi = d;
    #pragma unroll
    for (int mask = 1; mask < 32; mask <<= 1) {
        float ov = __shfl_xor(bv, mask, 32);
        int   oi = __shfl_xor(bi, mask, 32);
        if (ov > bv || (ov == bv && oi < bi)) { bv = ov; bi = oi; }
    }
    float dsel = __shfl(depth, bi, 32);
    if (d == 0) out[p] = dsel;
}

extern "C" void kernel_launch(void* const* d_in, const int* in_sizes, int n_in,
                              void* d_out, int out_size, void* d_ws, size_t ws_size,
                              hipStream_t stream) {
    const float* ref_feats  = (const float*)d_in[0];
    const float* src_feats  = (const float*)d_in[1];
    const float* proj       = (const float*)d_in[2];
    const float* depth_hypo = (const float*)d_in[3];
    const float* w_reg      = (const float*)d_in[4];
    float* out = (float*)d_out;

    size_t featB = (size_t)FEATSZ*sizeof(float);
    size_t needG = 2*featB + 96*sizeof(float);

    if (ws_size >= needG) {
        char* base = (char*)d_ws;
        float* srcT = (float*)base;                 base += featB;
        float* refT = (float*)base;                 base += featB;
        float* pw = (float*)base;
        hipLaunchKernelGGL(prep_kernel, dim3(2*TGRID + 1), dim3(256), 0, stream,
                           src_feats, ref_feats, proj, srcT, refT, pw);
        hipLaunchKernelGGL(mvs_kernel_g, dim3((NPIX*64)/256), dim3(256), 0, stream,
                           refT, srcT, depth_hypo, w_reg, pw, out);
    } else {
        float* pw = (float*)d_ws;
        hipLaunchKernelGGL(proj_setup_kernel, dim3(1), dim3(64), 0, stream, proj, pw);
        hipLaunchKernelGGL(mvs_kernel, dim3((NPIX*ND)/256), dim3(256), 0, stream,
                           ref_feats, src_feats, depth_hypo, w_reg, pw, out);
    }
}